// Round 1
// baseline (140.170 us; speedup 1.0000x reference)
//
#include <hip/hip_runtime.h>
#include <cfloat>
#include <cstdint>

#define NV 50257
#define NB 2048
#define NK 5
#define TOPK 10
#define NT 256

__device__ __forceinline__ void insert_top(float (&top)[TOPK], float v) {
    // precondition: v > top[TOPK-1]
    top[TOPK-1] = v;
#pragma unroll
    for (int i = TOPK - 1; i > 0; --i) {
        float a = top[i-1], b = top[i];
        top[i-1] = fmaxf(a, b);
        top[i]   = fminf(a, b);
    }
}

__global__ __launch_bounds__(NT) void embert_row_kernel(
        const float* __restrict__ probas,
        const int*   __restrict__ labels,
        float*       __restrict__ row_out) {
    const int row = blockIdx.x;
    const int tid = threadIdx.x;
    const float* __restrict__ p = probas + (size_t)row * NV;

    // labels for this row (block-uniform -> scalar loads)
    const int l0 = labels[row*NK + 0];
    const int l1 = labels[row*NK + 1];
    const int l2 = labels[row*NK + 2];
    const int l3 = labels[row*NK + 3];
    const int l4 = labels[row*NK + 4];

    float top[TOPK];
#pragma unroll
    for (int i = 0; i < TOPK; ++i) top[i] = -FLT_MAX;

    auto consider = [&](float v, int j) {
        if (v > top[TOPK-1]) {
            if (j != l0 && j != l1 && j != l2 && j != l3 && j != l4) {
                insert_top(top, v);
            }
        }
    };

    // Row base is only 4B-aligned (NV*4 % 16 == 4). Scalar prologue to 16B,
    // float4 main body, scalar tail.
    const int mis = (int)(((uintptr_t)p >> 2) & 3);   // misalignment in elements
    const int pre = (4 - mis) & 3;
    const int nvec = (NV - pre) >> 2;
    const int tail_start = pre + nvec * 4;

    if (tid < pre) consider(p[tid], tid);

    const float4* __restrict__ p4 = (const float4*)(p + pre);
    for (int vi = tid; vi < nvec; vi += NT) {
        float4 v = p4[vi];
        const int j = pre + vi * 4;
        consider(v.x, j);
        consider(v.y, j + 1);
        consider(v.z, j + 2);
        consider(v.w, j + 3);
    }

    if (tid < NV - tail_start) consider(p[tail_start + tid], tail_start + tid);

    // Block tree-merge of per-thread sorted top-10 lists through LDS.
    __shared__ float sm[NT][TOPK];
#pragma unroll
    for (int i = 0; i < TOPK; ++i) sm[tid][i] = top[i];
    __syncthreads();

    for (int off = NT / 2; off >= 1; off >>= 1) {
        if (tid < off) {
#pragma unroll
            for (int m = 0; m < TOPK; ++m) {
                float v = sm[tid + off][m];
                if (v > top[TOPK-1]) {
                    insert_top(top, v);
                } else {
                    break;  // partner list sorted desc: rest can't qualify
                }
            }
#pragma unroll
            for (int i = 0; i < TOPK; ++i) sm[tid][i] = top[i];
        }
        __syncthreads();
    }

    if (tid == 0) {
        float wrong_sum = 0.f;
#pragma unroll
        for (int i = 0; i < TOPK; ++i) wrong_sum += top[i];
        const float wrong_avg = wrong_sum * (1.0f / TOPK);

        // dedupe labels, average of labeled probas
        int ls[NK] = {l0, l1, l2, l3, l4};
        float csum = 0.f;
        int   n    = 0;
#pragma unroll
        for (int a = 0; a < NK; ++a) {
            bool dup = false;
#pragma unroll
            for (int b = 0; b < NK; ++b) {
                if (b < a) dup |= (ls[a] == ls[b]);
            }
            if (!dup) { csum += p[ls[a]]; ++n; }
        }
        row_out[row] = wrong_avg - csum / (float)n;
    }
}

__global__ __launch_bounds__(NT) void embert_reduce_kernel(
        const float* __restrict__ row_out,
        float*       __restrict__ out) {
    const int tid = threadIdx.x;
    float s = 0.f;
    for (int i = tid; i < NB; i += NT) s += row_out[i];
#pragma unroll
    for (int off = 32; off >= 1; off >>= 1) s += __shfl_down(s, off, 64);
    __shared__ float ws[NT / 64];
    if ((tid & 63) == 0) ws[tid >> 6] = s;
    __syncthreads();
    if (tid == 0) {
        float t = 0.f;
#pragma unroll
        for (int w = 0; w < NT / 64; ++w) t += ws[w];
        out[0] = t * (1.0f / NB);
    }
}

extern "C" void kernel_launch(void* const* d_in, const int* in_sizes, int n_in,
                              void* d_out, int out_size, void* d_ws, size_t ws_size,
                              hipStream_t stream) {
    const float* probas = (const float*)d_in[0];
    const int*   labels = (const int*)d_in[1];
    float* out = (float*)d_out;
    float* rows = (float*)d_ws;   // NB floats of scratch

    embert_row_kernel<<<NB, NT, 0, stream>>>(probas, labels, rows);
    embert_reduce_kernel<<<1, NT, 0, stream>>>(rows, out);
}

// Round 2
// 89.292 us; speedup vs baseline: 1.5698x; 1.5698x over previous
//
#include <hip/hip_runtime.h>
#include <cfloat>
#include <cstdint>

#define NV 50257
#define NB 2048
#define NK 5
#define TOPK 10
#define NT 256
#define CAP 1024
#define THR 0.99f

__device__ __forceinline__ void insert_top(float (&top)[TOPK], float v) {
    // precondition: v > top[TOPK-1]
    top[TOPK-1] = v;
#pragma unroll
    for (int i = TOPK - 1; i > 0; --i) {
        float a = top[i-1], b = top[i];
        top[i-1] = fmaxf(a, b);
        top[i]   = fminf(a, b);
    }
}

__global__ __launch_bounds__(NT, 8) void embert_row_kernel(
        const float* __restrict__ probas,
        const int*   __restrict__ labels,
        float*       __restrict__ row_out) {
    const int row = blockIdx.x;
    const int tid = threadIdx.x;
    const float* __restrict__ p = probas + (size_t)row * NV;

    __shared__ float cvals[CAP];
    __shared__ int   cidx[CAP];
    __shared__ int   cnt;
    __shared__ float sm[NT][TOPK];

    const int l0 = labels[row*NK + 0];
    const int l1 = labels[row*NK + 1];
    const int l2 = labels[row*NK + 2];
    const int l3 = labels[row*NK + 3];
    const int l4 = labels[row*NK + 4];

    if (tid == 0) cnt = 0;
    __syncthreads();

    // ---- Pass 1: collect candidates > THR into LDS (value + index) ----
    auto emit = [&](float v, int j) {
        if (v > THR) {
            int slot = atomicAdd(&cnt, 1);
            if (slot < CAP) { cvals[slot] = v; cidx[slot] = j; }
        }
    };

    // Row base is only 4B-aligned (NV*4 % 16 == 4): scalar prologue to 16B,
    // float4 main body, scalar tail.
    const int mis = (int)(((uintptr_t)p >> 2) & 3);
    const int pre = (4 - mis) & 3;
    const int nvec = (NV - pre) >> 2;
    const int tail_start = pre + nvec * 4;

    if (tid < pre) emit(p[tid], tid);

    const float4* __restrict__ p4 = (const float4*)(p + pre);
    for (int vi = tid; vi < nvec; vi += NT) {
        float4 v = p4[vi];
        const int j = pre + vi * 4;
        emit(v.x, j);
        emit(v.y, j + 1);
        emit(v.z, j + 2);
        emit(v.w, j + 3);
    }

    if (tid < NV - tail_start) emit(p[tail_start + tid], tail_start + tid);

    __syncthreads();
    const int n = cnt;
    const bool fast = (n >= TOPK + NK) && (n <= CAP);

    float top[TOPK];
#pragma unroll
    for (int i = 0; i < TOPK; ++i) top[i] = -FLT_MAX;

    if (fast) {
        // ---- Pass 2a: top-10 over ~n candidates, excluding label indices ----
        for (int c = tid; c < n; c += NT) {
            float v = cvals[c];
            int   j = cidx[c];
            if (v > top[TOPK-1]) {
                if (j != l0 && j != l1 && j != l2 && j != l3 && j != l4) {
                    insert_top(top, v);
                }
            }
        }
    } else {
        // ---- Fallback (correct for any input; never taken for uniform) ----
        auto consider = [&](float v, int j) {
            if (v > top[TOPK-1]) {
                if (j != l0 && j != l1 && j != l2 && j != l3 && j != l4) {
                    insert_top(top, v);
                }
            }
        };
        if (tid < pre) consider(p[tid], tid);
        for (int vi = tid; vi < nvec; vi += NT) {
            float4 v = p4[vi];
            const int j = pre + vi * 4;
            consider(v.x, j);
            consider(v.y, j + 1);
            consider(v.z, j + 2);
            consider(v.w, j + 3);
        }
        if (tid < NV - tail_start) consider(p[tail_start + tid], tail_start + tid);
    }

    // ---- Block tree-merge of per-thread sorted top-10 lists ----
#pragma unroll
    for (int i = 0; i < TOPK; ++i) sm[tid][i] = top[i];
    __syncthreads();

    for (int off = NT / 2; off >= 1; off >>= 1) {
        if (tid < off) {
#pragma unroll
            for (int m = 0; m < TOPK; ++m) {
                float v = sm[tid + off][m];
                if (v > top[TOPK-1]) {
                    insert_top(top, v);
                } else {
                    break;  // partner list sorted desc
                }
            }
#pragma unroll
            for (int i = 0; i < TOPK; ++i) sm[tid][i] = top[i];
        }
        __syncthreads();
    }

    if (tid == 0) {
        float wrong_sum = 0.f;
#pragma unroll
        for (int i = 0; i < TOPK; ++i) wrong_sum += top[i];
        const float wrong_avg = wrong_sum * (1.0f / TOPK);

        int ls[NK] = {l0, l1, l2, l3, l4};
        float csum = 0.f;
        int   nn   = 0;
#pragma unroll
        for (int a = 0; a < NK; ++a) {
            bool dup = false;
#pragma unroll
            for (int b = 0; b < NK; ++b) {
                if (b < a) dup |= (ls[a] == ls[b]);
            }
            if (!dup) { csum += p[ls[a]]; ++nn; }
        }
        row_out[row] = wrong_avg - csum / (float)nn;
    }
}

__global__ __launch_bounds__(NT) void embert_reduce_kernel(
        const float* __restrict__ row_out,
        float*       __restrict__ out) {
    const int tid = threadIdx.x;
    float s = 0.f;
    for (int i = tid; i < NB; i += NT) s += row_out[i];
#pragma unroll
    for (int off = 32; off >= 1; off >>= 1) s += __shfl_down(s, off, 64);
    __shared__ float ws[NT / 64];
    if ((tid & 63) == 0) ws[tid >> 6] = s;
    __syncthreads();
    if (tid == 0) {
        float t = 0.f;
#pragma unroll
        for (int w = 0; w < NT / 64; ++w) t += ws[w];
        out[0] = t * (1.0f / NB);
    }
}

extern "C" void kernel_launch(void* const* d_in, const int* in_sizes, int n_in,
                              void* d_out, int out_size, void* d_ws, size_t ws_size,
                              hipStream_t stream) {
    const float* probas = (const float*)d_in[0];
    const int*   labels = (const int*)d_in[1];
    float* out = (float*)d_out;
    float* rows = (float*)d_ws;   // NB floats of scratch

    embert_row_kernel<<<NB, NT, 0, stream>>>(probas, labels, rows);
    embert_reduce_kernel<<<1, NT, 0, stream>>>(rows, out);
}